// Round 5
// baseline (108.873 us; speedup 1.0000x reference)
//
#include <hip/hip_runtime.h>

typedef __attribute__((ext_vector_type(8))) short short8;
typedef __attribute__((ext_vector_type(4))) float f32x4;

#define NB 8
#define NC 256
#define NH 4
#define ND 64
#define NN 1024
#define OC3 768

__device__ __forceinline__ unsigned short f2bf(float f) {
  union { float f; unsigned int u; } a;
  a.f = f;
  unsigned int r = a.u + 0x7fffu + ((a.u >> 16) & 1u);
  return (unsigned short)(r >> 16);
}

// pack two fp32 -> bf16x2 (round-to-nearest): add 0x8000, perm high halves.
__device__ __forceinline__ unsigned int pkbf(float lo, float hi) {
  union { float f; unsigned int u; } a, b;
  a.f = lo; b.f = hi;
  return __builtin_amdgcn_perm(b.u + 0x8000u, a.u + 0x8000u, 0x07060302u);
}

// async global->LDS, 16 B per lane; HW adds lane*16 to the wave-uniform base.
typedef const unsigned int __attribute__((address_space(1)))* gp_t;
typedef unsigned int __attribute__((address_space(3)))* lp_t;
__device__ __forceinline__ void glds16(const unsigned short* g, unsigned short* l) {
  __builtin_amdgcn_global_load_lds((gp_t)g, (lp_t)l, 16, 0, 0);
}

// ---------------------------------------------------------------------------
// fused transpose+cast for all three inputs (one launch):
//  z<8 : x batch z (256,1024) -> xs (1024,256)
//  z==8: Wp (256,768) -> WpT ; z==9: Wo (256,256) -> WoT
// ---------------------------------------------------------------------------
__global__ __launch_bounds__(256) void trans_all(
    const float* __restrict__ x, const float* __restrict__ Wp,
    const float* __restrict__ Wo, unsigned short* __restrict__ xs,
    unsigned short* __restrict__ WpT, unsigned short* __restrict__ WoT) {
  __shared__ float T[64][65];
  int z = blockIdx.z;
  const float* in; unsigned short* out; int R, S;
  if (z < 8) { in = x + (size_t)z * NC * NN; out = xs + (size_t)z * NC * NN; R = NC; S = NN; }
  else if (z == 8) { if (blockIdx.x >= 12) return; in = Wp; out = WpT; R = NC; S = OC3; }
  else { if (blockIdx.x >= 4) return; in = Wo; out = WoT; R = NC; S = NC; }
  int s0 = blockIdx.x * 64, r0 = blockIdx.y * 64;
  int t = threadIdx.x;
  {
    int ri = t >> 2, sb = t & 3;
    const float* p = in + (size_t)(r0 + ri) * S + s0 + sb * 16;
    float4 v0 = *(const float4*)(p);
    float4 v1 = *(const float4*)(p + 4);
    float4 v2 = *(const float4*)(p + 8);
    float4 v3 = *(const float4*)(p + 12);
    float vv[16] = {v0.x, v0.y, v0.z, v0.w, v1.x, v1.y, v1.z, v1.w,
                    v2.x, v2.y, v2.z, v2.w, v3.x, v3.y, v3.z, v3.w};
#pragma unroll
    for (int e = 0; e < 16; ++e) T[ri][sb * 16 + e] = vv[e];
  }
  __syncthreads();
  {
    int so = t >> 2, rb = t & 3;
    union { unsigned short us[16]; uint4 v[2]; } pk;
#pragma unroll
    for (int e = 0; e < 16; ++e) pk.us[e] = f2bf(T[rb * 16 + e][so]);
    uint4* dst = (uint4*)(out + (size_t)(s0 + so) * R + r0 + rb * 16);
    dst[0] = pk.v[0];
    dst[1] = pk.v[1];
  }
}

// ---------------------------------------------------------------------------
// GEMM1: qkv = xs(8192x256) @ Wp(256x768) + bp.  m97 recipe: unpadded 64x64
// LDS tiles staged via global_load_lds(16B), 2-barrier K-loop.  Epilogue
// writes Q/K/V in MFMA FRAGMENT-MAJOR layout:
//  Qf: [bh][it16][rg4][ks2][l64][e8]   (Q pre-scaled by 0.125*log2(e))
//  Kf: [bh][jt16][ks2*4+js][l64][e8]
//  Vf: [bh][jt16][kv2*4+dt][l64][e8]
// ---------------------------------------------------------------------------
__global__ __launch_bounds__(256) void gemm_qkv(
    const unsigned short* __restrict__ xs, const unsigned short* __restrict__ WpT,
    const float* __restrict__ bp,
    unsigned short* __restrict__ Qf, unsigned short* __restrict__ Kf,
    unsigned short* __restrict__ Vf) {
  __shared__ __attribute__((aligned(16))) unsigned short Al[64 * 64];
  __shared__ __attribute__((aligned(16))) unsigned short Bl[64 * 64];
  int nt = blockIdx.x, mt = blockIdx.y;
  int t = threadIdx.x, w = t >> 6, l = t & 63, q = l >> 4, c = l & 15;
  f32x4 acc[4] = {{0, 0, 0, 0}, {0, 0, 0, 0}, {0, 0, 0, 0}, {0, 0, 0, 0}};
  const unsigned short* Arow = xs + (size_t)(mt * 64) * NC;
  const unsigned short* Brow = WpT + (size_t)(nt * 64) * NC;
  for (int k0 = 0; k0 < NC; k0 += 64) {
    __syncthreads();  // prior ds_reads drained (lgkm) before overwrite
#pragma unroll
    for (int it = 0; it < 2; ++it) {
      int base = it * 256 + w * 64;        // wave-uniform element group
      int row = (base + l) >> 3, col = ((base + l) & 7) * 8;
      glds16(Arow + (size_t)row * NC + k0 + col, &Al[base * 8]);
      glds16(Brow + (size_t)row * NC + k0 + col, &Bl[base * 8]);
    }
    __syncthreads();  // vmcnt drained; tiles visible
#pragma unroll
    for (int ks = 0; ks < 2; ++ks) {
      short8 a = *(const short8*)&Al[(w * 16 + c) * 64 + ks * 32 + q * 8];
#pragma unroll
      for (int ct = 0; ct < 4; ++ct) {
        short8 b = *(const short8*)&Bl[(ct * 16 + c) * 64 + ks * 32 + q * 8];
        acc[ct] = __builtin_amdgcn_mfma_f32_16x16x32_bf16(a, b, acc[ct], 0, 0, 0);
      }
    }
  }
  int o0 = nt * 64;
  int h = o0 / 192, rem = o0 % 192;
  int b = mt >> 4, itl = mt & 15;
  int bh = b * NH + h;
  size_t rbase = (size_t)bh * 65536;
#pragma unroll
  for (int ct = 0; ct < 4; ++ct) {
    float bias = bp[o0 + ct * 16 + c];
#pragma unroll
    for (int r = 0; r < 4; ++r) acc[ct][r] += bias;
  }
  if (rem < 128) {
    // acc[ct][r] = value at (row n = mt*64 + w*16 + q*4 + r, col d = ct*16+c)
    unsigned short* dst = (rem == 0) ? Qf : Kf;
    float sc = (rem == 0) ? 0.18033688011112042f : 1.0f;  // 0.125*log2(e)
#pragma unroll
    for (int ct = 0; ct < 4; ++ct) {
      int ks = ct >> 1, qf = (ct & 1) * 2 + (c >> 3), e = c & 7;
      size_t fbase = (rem == 0)
          ? rbase + (size_t)((itl * 4 + w) * 2 + ks) * 512
          : rbase + (size_t)(itl * 8 + ks * 4 + w) * 512;
      size_t off = fbase + (size_t)(qf * 16) * 8 + e;
#pragma unroll
      for (int r = 0; r < 4; ++r)
        dst[off + (q * 4 + r) * 8] = f2bf(acc[ct][r] * sc);
    }
  } else {
    // V: row n is the j index, col d the feature. frag kv=w>>1, lane=(ql,c).
    int kv = w >> 1, ql = (w & 1) * 2 + (q >> 1);
#pragma unroll
    for (int ct = 0; ct < 4; ++ct) {
      size_t fbase = rbase + (size_t)(itl * 8 + kv * 4 + ct) * 512 + (ql * 16 + c) * 8
                   + (q & 1) * 4;
      uint2 pk2 = {pkbf(acc[ct][0], acc[ct][1]), pkbf(acc[ct][2], acc[ct][3])};
      *(uint2*)&Vf[fbase] = pk2;  // e = (q&1)*4 + r, r=0..3 contiguous
    }
  }
}

// ---------------------------------------------------------------------------
// attn v4 (frozen from round 4): fragment-major Q/K/V; K/V double-buffered
// via global_load_lds(16B), one barrier per j-tile; S^T = K Q^T so each lane
// owns one i-row; exp2 softmax, per-lane row-sum, no max-subtraction.
// ---------------------------------------------------------------------------
__global__ __launch_bounds__(256) void attn(
    const unsigned short* __restrict__ Qf, const unsigned short* __restrict__ Kf,
    const unsigned short* __restrict__ Vf, unsigned short* __restrict__ O) {
  __shared__ __attribute__((aligned(16))) unsigned short Kl[2][4096];
  __shared__ __attribute__((aligned(16))) unsigned short Vl[2][4096];
  __shared__ __attribute__((aligned(16))) unsigned short Pl[4][1024];
  int B = blockIdx.x;
  int bh = (B & 7) + 8 * ((B >> 3) & 3);  // same bh -> same XCD (blk%8 rr)
  int it = B >> 5;
  int t = threadIdx.x, w = t >> 6, l = t & 63, q = l >> 4, c = l & 15;
  const unsigned short* Qt = Qf + (size_t)bh * 65536 + (size_t)(it * 4 + w) * 1024;
  short8 bq0 = *(const short8*)(Qt + l * 8);
  short8 bq1 = *(const short8*)(Qt + 512 + l * 8);
  const unsigned short* Kt = Kf + (size_t)bh * 65536;
  const unsigned short* Vt = Vf + (size_t)bh * 65536;

#pragma unroll
  for (int m = 0; m < 2; ++m) {
    int ch = (m * 4 + w) * 512;
    glds16(Kt + ch + l * 8, &Kl[0][ch]);
    glds16(Vt + ch + l * 8, &Vl[0][ch]);
  }

  float lsum = 0.f;
  f32x4 oacc[4] = {{0, 0, 0, 0}, {0, 0, 0, 0}, {0, 0, 0, 0}, {0, 0, 0, 0}};
  unsigned short* Pw = &Pl[w][0];
  int p = 0;
  for (int jt = 0; jt < 16; ++jt) {
    __syncthreads();  // staging of buf p complete; all waves done with p^1
    if (jt < 15) {
      const unsigned short* ksn = Kt + (size_t)(jt + 1) * 4096;
      const unsigned short* vsn = Vt + (size_t)(jt + 1) * 4096;
#pragma unroll
      for (int m = 0; m < 2; ++m) {
        int ch = (m * 4 + w) * 512;
        glds16(ksn + ch + l * 8, &Kl[p ^ 1][ch]);
        glds16(vsn + ch + l * 8, &Vl[p ^ 1][ch]);
      }
    }
    // S^T tile: lane(q,c) reg r = S[i = it*64+w*16+c][j = jt*64+js*16+q*4+r]
    f32x4 sT[4] = {{0, 0, 0, 0}, {0, 0, 0, 0}, {0, 0, 0, 0}, {0, 0, 0, 0}};
#pragma unroll
    for (int ks = 0; ks < 2; ++ks) {
      short8 bq = ks ? bq1 : bq0;
#pragma unroll
      for (int js = 0; js < 4; ++js) {
        short8 ka = *(const short8*)&Kl[p][(ks * 4 + js) * 512 + l * 8];
        sT[js] = __builtin_amdgcn_mfma_f32_16x16x32_bf16(ka, bq, sT[js], 0, 0, 0);
      }
    }
    // exp2 + per-lane row-sum + pack P into fragment-major LDS
#pragma unroll
    for (int js = 0; js < 4; ++js) {
      float e0 = __builtin_amdgcn_exp2f(sT[js][0]);
      float e1 = __builtin_amdgcn_exp2f(sT[js][1]);
      float e2 = __builtin_amdgcn_exp2f(sT[js][2]);
      float e3 = __builtin_amdgcn_exp2f(sT[js][3]);
      lsum += (e0 + e1) + (e2 + e3);
      int base = (js >> 1) * 512 + (((js & 1) * 2 + (q >> 1)) * 16 + c) * 8 + (q & 1) * 4;
      *(unsigned int*)&Pw[base] = pkbf(e0, e1);
      *(unsigned int*)&Pw[base + 2] = pkbf(e2, e3);
    }
    // O += P V (A-frag read back at lane*16; V frags likewise)
#pragma unroll
    for (int kv = 0; kv < 2; ++kv) {
      short8 pa = *(const short8*)&Pw[kv * 512 + l * 8];
#pragma unroll
      for (int dt = 0; dt < 4; ++dt) {
        short8 vv = *(const short8*)&Vl[p][(kv * 4 + dt) * 512 + l * 8];
        oacc[dt] = __builtin_amdgcn_mfma_f32_16x16x32_bf16(pa, vv, oacc[dt], 0, 0, 0);
      }
    }
    p ^= 1;
  }
  lsum += __shfl_xor(lsum, 16);
  lsum += __shfl_xor(lsum, 32);
  float invr[4];
#pragma unroll
  for (int r = 0; r < 4; ++r) invr[r] = 1.0f / __shfl(lsum, q * 4 + r, 64);
  int b = bh >> 2, h = bh & 3;
#pragma unroll
  for (int dt = 0; dt < 4; ++dt)
#pragma unroll
    for (int r = 0; r < 4; ++r) {
      int i = it * 64 + w * 16 + q * 4 + r;
      O[((size_t)b * NN + i) * NC + h * ND + dt * 16 + c] = f2bf(oacc[dt][r] * invr[r]);
    }
}

// ---------------------------------------------------------------------------
// GEMM2: res = O @ Wo + bo; out = transpose(res) + x.  m97-style staging.
// ---------------------------------------------------------------------------
__global__ __launch_bounds__(256) void gemm_out(
    const unsigned short* __restrict__ O, const unsigned short* __restrict__ WoT,
    const float* __restrict__ bo, const float* __restrict__ x,
    float* __restrict__ out) {
  __shared__ __attribute__((aligned(16))) unsigned short Al[64 * 64];
  __shared__ __attribute__((aligned(16))) unsigned short Bl[64 * 64];
  __shared__ float Tl[64 * 65];
  int nt = blockIdx.x, mt = blockIdx.y;
  int t = threadIdx.x, w = t >> 6, l = t & 63, q = l >> 4, c = l & 15;
  f32x4 acc[4] = {{0, 0, 0, 0}, {0, 0, 0, 0}, {0, 0, 0, 0}, {0, 0, 0, 0}};
  const unsigned short* Arow = O + (size_t)(mt * 64) * NC;
  const unsigned short* Brow = WoT + (size_t)(nt * 64) * NC;
  for (int k0 = 0; k0 < NC; k0 += 64) {
    __syncthreads();
#pragma unroll
    for (int it = 0; it < 2; ++it) {
      int base = it * 256 + w * 64;
      int row = (base + l) >> 3, col = ((base + l) & 7) * 8;
      glds16(Arow + (size_t)row * NC + k0 + col, &Al[base * 8]);
      glds16(Brow + (size_t)row * NC + k0 + col, &Bl[base * 8]);
    }
    __syncthreads();
#pragma unroll
    for (int ks = 0; ks < 2; ++ks) {
      short8 a = *(const short8*)&Al[(w * 16 + c) * 64 + ks * 32 + q * 8];
#pragma unroll
      for (int ct = 0; ct < 4; ++ct) {
        short8 b = *(const short8*)&Bl[(ct * 16 + c) * 64 + ks * 32 + q * 8];
        acc[ct] = __builtin_amdgcn_mfma_f32_16x16x32_bf16(a, b, acc[ct], 0, 0, 0);
      }
    }
  }
#pragma unroll
  for (int ct = 0; ct < 4; ++ct) {
    float bias = bo[nt * 64 + ct * 16 + c];
#pragma unroll
    for (int r = 0; r < 4; ++r)
      Tl[(ct * 16 + c) * 65 + w * 16 + q * 4 + r] = acc[ct][r] + bias;
  }
  __syncthreads();
  int b = (mt * 64) >> 10, n0 = (mt * 64) & 1023;
  int cl = t >> 2, nb = t & 3;
  float v[16];
#pragma unroll
  for (int e = 0; e < 16; ++e) v[e] = Tl[cl * 65 + nb * 16 + e];
  size_t base = ((size_t)(b * NC + nt * 64 + cl)) * NN + n0 + nb * 16;
#pragma unroll
  for (int g = 0; g < 4; ++g) {
    float4 xv = *(const float4*)(x + base + g * 4);
    float4 ov;
    ov.x = v[g * 4 + 0] + xv.x;
    ov.y = v[g * 4 + 1] + xv.y;
    ov.z = v[g * 4 + 2] + xv.z;
    ov.w = v[g * 4 + 3] + xv.w;
    *(float4*)(out + base + g * 4) = ov;
  }
}

// ---------------------------------------------------------------------------
extern "C" void kernel_launch(void* const* d_in, const int* in_sizes, int n_in,
                              void* d_out, int out_size, void* d_ws, size_t ws_size,
                              hipStream_t stream) {
  const float* x = (const float*)d_in[0];
  const float* Wp = (const float*)d_in[1];
  const float* bp = (const float*)d_in[2];
  const float* Wo = (const float*)d_in[3];
  const float* bo = (const float*)d_in[4];
  float* out = (float*)d_out;
  char* ws = (char*)d_ws;
  unsigned short* xs  = (unsigned short*)(ws);             // 4 MB  (B,N,C) bf16
  unsigned short* WpT = (unsigned short*)(ws + 4194304);   // 384KB (768,256)
  unsigned short* WoT = (unsigned short*)(ws + 4587520);   // 128KB (256,256)
  unsigned short* Qfr = (unsigned short*)(ws + 4718592);   // 4 MB  frag-major
  unsigned short* Kfr = (unsigned short*)(ws + 8912896);   // 4 MB  frag-major
  unsigned short* Vfr = (unsigned short*)(ws + 13107200);  // 4 MB  frag-major
  unsigned short* Ob  = (unsigned short*)(ws + 17301504);  // 4 MB  (B,N,C)

  hipLaunchKernelGGL(trans_all, dim3(16, 4, 10), dim3(256), 0, stream,
                     x, Wp, Wo, xs, WpT, WoT);
  hipLaunchKernelGGL(gemm_qkv, dim3(12, 128), dim3(256), 0, stream, xs, WpT, bp,
                     Qfr, Kfr, Vfr);
  hipLaunchKernelGGL(attn, dim3(512), dim3(256), 0, stream, Qfr, Kfr, Vfr, Ob);
  hipLaunchKernelGGL(gemm_out, dim3(4, 128), dim3(256), 0, stream, Ob, WoT, bo, x, out);
}